// Round 11
// baseline (135.589 us; speedup 1.0000x reference)
//
#include <hip/hip_runtime.h>
#include <stdint.h>
#include <math.h>

using short8   = __attribute__((ext_vector_type(8))) short;
using ushort4v = __attribute__((ext_vector_type(4))) unsigned short;
using f32x4    = __attribute__((ext_vector_type(4))) float;
using uint4v   = __attribute__((ext_vector_type(4))) unsigned int;

#define B_ 2
#define S_ 64
#define K_ 64
#define D_ 256
#define C_ 32
#define N_ 4096  /* S_*K_ */
#define LOG2E 1.4426950408889634f

__device__ __forceinline__ float b2f(unsigned short u) {
    unsigned int v = ((unsigned int)u) << 16;
    return __builtin_bit_cast(float, v);
}
__device__ __forceinline__ unsigned short f2b(float f) {   // RNE f32->bf16
    unsigned int x = __builtin_bit_cast(unsigned int, f);
    x += 0x7fffu + ((x >> 16) & 1u);
    return (unsigned short)(x >> 16);
}
__device__ __forceinline__ unsigned int cvtpk(float a, float b) {  // [a|b] bf16x2
    unsigned int r;
    asm("v_cvt_pk_bf16_f32 %0, %1, %2" : "=v"(r) : "v"(a), "v"(b));
    return r;
}

// ---------------------------------------------------------------------------
// Kernel 0: W/bias pre-convert. Concatenated out-channels: 0-31 Q (x log2e),
// 32-63 K, 64-319 V. Wh/Wl bf16 hi/lo planes [320][256]; bcat f32[320].
// ---------------------------------------------------------------------------
__global__ __launch_bounds__(256) void wcvt_kernel(
    const float* __restrict__ Wq, const float* __restrict__ bq,
    const float* __restrict__ Wk, const float* __restrict__ bk,
    const float* __restrict__ Wv, const float* __restrict__ bv,
    unsigned short* __restrict__ Wh, unsigned short* __restrict__ Wl,
    float* __restrict__ bcat)
{
    int oc = blockIdx.x;            // 0..319
    int d  = threadIdx.x;           // 0..255
    float w;
    if (oc < 32)       w = Wq[oc * 256 + d] * LOG2E;
    else if (oc < 64)  w = Wk[(oc - 32) * 256 + d];
    else               w = Wv[(oc - 64) * 256 + d];
    unsigned short h = f2b(w);
    Wh[oc * 256 + d] = h;
    Wl[oc * 256 + d] = f2b(w - b2f(h));
    if (d == 0) {
        float bb;
        if (oc < 32)      bb = bq[oc] * LOG2E;
        else if (oc < 64) bb = bk[oc - 32];
        else              bb = bv[oc - 64];
        bcat[oc] = bb;
    }
}

// ---------------------------------------------------------------------------
// Kernel 1: QKV projections. 512 blocks (one 16-token tile) x 4 waves.
// x staged once in LDS as hi/lo bf16 (XOR-swizzled); W from pre-converted
// planes. Q,K stored [B][N][C] hi/lo. V chunk-interleaved [B][N/32][D][32]
// with SLOT-PERMUTED in-chunk order: token j (in-chunk) at slot
// s = 8*((j&15)>>2) + ((j&16)>>2) + (j&3)  -- matches attn's register-P
// fragment layout so PV needs no P shuffle at all.
// ---------------------------------------------------------------------------
__global__ __launch_bounds__(256) void qkv_kernel(
    const float* __restrict__ x,
    const unsigned short* __restrict__ Wh, const unsigned short* __restrict__ Wl,
    const float* __restrict__ bcat,
    unsigned short* __restrict__ Qh, unsigned short* __restrict__ Ql,
    unsigned short* __restrict__ Kh, unsigned short* __restrict__ Kl,
    unsigned short* __restrict__ Vm)
{
    __shared__ unsigned short lxh[16 * 256];   // [tok][d] bf16-hi, swizzled
    __shared__ unsigned short lxl[16 * 256];   // bf16-lo

    int tid = threadIdx.x;
    int bid = blockIdx.x;
    int b  = bid >> 8;
    int n0 = (bid & 255) << 4;

    // ---- stage x tile: thread -> (token tt, 16-d group dg0) ----
    {
        int tt = tid >> 4, dg0 = (tid & 15) * 16;
        int n = n0 + tt;
        int s = n & 63, kk = n >> 6;
        const float* xr = x + (((size_t)(b * S_ + s)) * K_ + kk) * D_ + dg0;
        short8 h0, l0, h1, l1;
#pragma unroll
        for (int e = 0; e < 8; ++e) {
            float v = xr[e];
            unsigned short hh = f2b(v);
            h0[e] = (short)hh; l0[e] = (short)f2b(v - b2f(hh));
        }
#pragma unroll
        for (int e = 0; e < 8; ++e) {
            float v = xr[8 + e];
            unsigned short hh = f2b(v);
            h1[e] = (short)hh; l1[e] = (short)f2b(v - b2f(hh));
        }
        int m0 = dg0 >> 3;                       // 16B-granule index (even)
        int sw0 = ((m0 ^ (tt & 7)) << 3);
        int sw1 = (((m0 + 1) ^ (tt & 7)) << 3);
        *(short8*)(lxh + tt * 256 + sw0) = h0;
        *(short8*)(lxh + tt * 256 + sw1) = h1;
        *(short8*)(lxl + tt * 256 + sw0) = l0;
        *(short8*)(lxl + tt * 256 + sw1) = l1;
    }
    __syncthreads();

    int wave = tid >> 6, lane = tid & 63;
    int col = lane & 15, g = lane >> 4;

#pragma unroll
    for (int i = 0; i < 5; ++i) {
        int ct = wave + i * 4;                   // 0..19
        int oc0 = ct * 16;
        const unsigned short* whr = Wh + (size_t)(oc0 + col) * 256;
        const unsigned short* wlr = Wl + (size_t)(oc0 + col) * 256;
        f32x4 acc = {0.f, 0.f, 0.f, 0.f};

        if (ct < 4) {                            // Q/K: split-bf16 3-chain
#pragma unroll
            for (int dc = 0; dc < 8; ++dc) {
                int sw = (((dc * 4 + g) ^ (col & 7)) << 3);
                short8 xh8 = *(const short8*)(lxh + col * 256 + sw);
                short8 xl8 = *(const short8*)(lxl + col * 256 + sw);
                short8 wh8 = *(const short8*)(whr + dc * 32 + g * 8);
                short8 wl8 = *(const short8*)(wlr + dc * 32 + g * 8);
                acc = __builtin_amdgcn_mfma_f32_16x16x32_bf16(xl8, wh8, acc, 0, 0, 0);
                acc = __builtin_amdgcn_mfma_f32_16x16x32_bf16(xh8, wl8, acc, 0, 0, 0);
                acc = __builtin_amdgcn_mfma_f32_16x16x32_bf16(xh8, wh8, acc, 0, 0, 0);
            }
            float bb = bcat[oc0 + col];
            unsigned short* Th = (ct < 2) ? Qh : Kh;
            unsigned short* Tl = (ct < 2) ? Ql : Kl;
            int c0 = (ct & 1) * 16;
#pragma unroll
            for (int r = 0; r < 4; ++r) {
                int tok = n0 + g * 4 + r;
                float v = acc[r] + bb;
                unsigned short hh = f2b(v);
                size_t idx = ((size_t)b * N_ + tok) * C_ + c0 + col;
                Th[idx] = hh;
                Tl[idx] = f2b(v - b2f(hh));
            }
        } else {                                 // V: single bf16
#pragma unroll
            for (int dc = 0; dc < 8; ++dc) {
                int sw = (((dc * 4 + g) ^ (col & 7)) << 3);
                short8 xh8 = *(const short8*)(lxh + col * 256 + sw);
                short8 wh8 = *(const short8*)(whr + dc * 32 + g * 8);
                acc = __builtin_amdgcn_mfma_f32_16x16x32_bf16(xh8, wh8, acc, 0, 0, 0);
            }
            float bb = bcat[oc0 + col];
            int c0 = oc0 - 64;
            ushort4v st;
#pragma unroll
            for (int r = 0; r < 4; ++r) st[r] = f2b(acc[r] + bb);
            int tok0 = n0 + g * 4;
            int s0 = 8 * g + ((n0 & 16) >> 2);   // slot-permuted in-chunk pos
            size_t vaddr = (((size_t)b * (N_ / 32) + (tok0 >> 5)) * D_ + c0 + col) * 32
                         + s0;
            *(ushort4v*)(Vm + vaddr) = st;
        }
    }
}

// ---------------------------------------------------------------------------
// Kernel 2: flash attention, 128-q tiles x key-split-4, barrier-free,
// REGISTER-ONLY P: slot permutation makes each lane's own packed scores the
// exact PV B-fragment (slot s=8g+e <-> key (e<4)?4g+e:16+4g+(e&3); V stored
// with the same permutation). No LDS, no cross-lane P exchange, no lgkmcnt.
// 256 blocks: bid&7=(b*4+ks) per XCD; 8 waves = 4 q-quarters x 2 d-halves.
// exp2-domain softmax (Q pre-scaled), no-max; l reduced once after the loop.
// ---------------------------------------------------------------------------
__global__ __launch_bounds__(512, 2) void attn_kernel(
    const unsigned short* __restrict__ Qh, const unsigned short* __restrict__ Ql,
    const unsigned short* __restrict__ Kh, const unsigned short* __restrict__ Kl,
    const unsigned short* __restrict__ Vm,
    float* __restrict__ O_part, float* __restrict__ lsum_part)
{
    int tid  = threadIdx.x;
    int wave = tid >> 6;
    int lane = tid & 63;
    int col = lane & 15, g = lane >> 4;
    int qq = wave >> 1;           // q-quarter 0..3
    int dh = wave & 1;            // d-half 0..1
    int dbase = dh * 128;

    int bid = blockIdx.x;
    int x7 = bid & 7;
    int b  = x7 >> 2;
    int ks = x7 & 3;
    int qt = bid >> 3;            // 0..31 (q-tile within batch)
    int q0 = qt * 128 + qq * 32;
    int jbase = ks * (N_ / 4);

    size_t qoff0 = ((size_t)b * N_ + q0 + col) * C_ + g * 8;
    size_t qoff1 = ((size_t)b * N_ + q0 + 16 + col) * C_ + g * 8;
    short8 qfh0 = *(const short8*)(Qh + qoff0);
    short8 qfl0 = *(const short8*)(Ql + qoff0);
    short8 qfh1 = *(const short8*)(Qh + qoff1);
    short8 qfl1 = *(const short8*)(Ql + qoff1);

    f32x4 acc[2][8];
#pragma unroll
    for (int qs = 0; qs < 2; ++qs)
#pragma unroll
        for (int dt = 0; dt < 8; ++dt) acc[qs][dt] = (f32x4){0.f, 0.f, 0.f, 0.f};
    float l_run0 = 0.f, l_run1 = 0.f;   // per-lane partials (reduced at end)

    const unsigned short* kbh = Kh + (size_t)b * N_ * C_;
    const unsigned short* kbl = Kl + (size_t)b * N_ * C_;
    const unsigned short* vb  = Vm + (size_t)b * N_ * D_;   // [N/32][D][32]

    auto kaddr0 = [&](int it) { return (size_t)(jbase + it * 32 + col) * C_ + g * 8; };
    auto kaddr1 = [&](int it) { return (size_t)(jbase + it * 32 + 16 + col) * C_ + g * 8; };
    auto vaddr  = [&](int it) {
        return (size_t)(ks * 32 + it) * (D_ * 32) + (size_t)(dbase + col) * 32 + g * 8;
    };

    // prologue: K(0), V(0)
    short8 kh0 = *(const short8*)(kbh + kaddr0(0));
    short8 kl0 = *(const short8*)(kbl + kaddr0(0));
    short8 kh1 = *(const short8*)(kbh + kaddr1(0));
    short8 kl1 = *(const short8*)(kbl + kaddr1(0));
    short8 vcur[8];
    {
        const unsigned short* vp = vb + vaddr(0);
#pragma unroll
        for (int dt = 0; dt < 8; ++dt)
            vcur[dt] = *(const short8*)(vp + dt * (16 * 32));
    }

#pragma unroll 2
    for (int it = 0; it < 32; ++it) {
        // issue next iteration's K and V loads first (hide under compute)
        short8 nkh0, nkl0, nkh1, nkl1, vnxt[8];
        int itn = (it + 1 < 32) ? it + 1 : 0;
        nkh0 = *(const short8*)(kbh + kaddr0(itn));
        nkl0 = *(const short8*)(kbl + kaddr0(itn));
        nkh1 = *(const short8*)(kbh + kaddr1(itn));
        nkl1 = *(const short8*)(kbl + kaddr1(itn));
        {
            const unsigned short* vp = vb + vaddr(itn);
#pragma unroll
            for (int dt = 0; dt < 8; ++dt)
                vnxt[dt] = *(const short8*)(vp + dt * (16 * 32));
        }

        // QK^T (split-bf16 3-chain): D[key][q], exp2-domain scores
        f32x4 z = {0.f, 0.f, 0.f, 0.f};
        f32x4 s00 = __builtin_amdgcn_mfma_f32_16x16x32_bf16(kl0, qfh0, z, 0, 0, 0);
        s00 = __builtin_amdgcn_mfma_f32_16x16x32_bf16(kh0, qfl0, s00, 0, 0, 0);
        s00 = __builtin_amdgcn_mfma_f32_16x16x32_bf16(kh0, qfh0, s00, 0, 0, 0);
        f32x4 s01 = __builtin_amdgcn_mfma_f32_16x16x32_bf16(kl1, qfh0, z, 0, 0, 0);
        s01 = __builtin_amdgcn_mfma_f32_16x16x32_bf16(kh1, qfl0, s01, 0, 0, 0);
        s01 = __builtin_amdgcn_mfma_f32_16x16x32_bf16(kh1, qfh0, s01, 0, 0, 0);
        f32x4 s10 = __builtin_amdgcn_mfma_f32_16x16x32_bf16(kl0, qfh1, z, 0, 0, 0);
        s10 = __builtin_amdgcn_mfma_f32_16x16x32_bf16(kh0, qfl1, s10, 0, 0, 0);
        s10 = __builtin_amdgcn_mfma_f32_16x16x32_bf16(kh0, qfh1, s10, 0, 0, 0);
        f32x4 s11 = __builtin_amdgcn_mfma_f32_16x16x32_bf16(kl1, qfh1, z, 0, 0, 0);
        s11 = __builtin_amdgcn_mfma_f32_16x16x32_bf16(kh1, qfl1, s11, 0, 0, 0);
        s11 = __builtin_amdgcn_mfma_f32_16x16x32_bf16(kh1, qfh1, s11, 0, 0, 0);

        // p = exp2(s'); |s'| <~50, clamp 80 is pure safety
        float pa[4], pc[4], pe[4], pg[4];
#pragma unroll
        for (int r = 0; r < 4; ++r) {
            pa[r] = exp2f(fminf(s00[r], 80.f));
            pc[r] = exp2f(fminf(s01[r], 80.f));
            pe[r] = exp2f(fminf(s10[r], 80.f));
            pg[r] = exp2f(fminf(s11[r], 80.f));
        }
        l_run0 += (pa[0] + pa[1]) + (pa[2] + pa[3]) + (pc[0] + pc[1]) + (pc[2] + pc[3]);
        l_run1 += (pe[0] + pe[1]) + (pe[2] + pe[3]) + (pg[0] + pg[1]) + (pg[2] + pg[3]);

        // pack P straight into PV B-fragments (slot-permuted; zero shuffle)
        uint4v u0, u1;
        u0[0] = cvtpk(pa[0], pa[1]); u0[1] = cvtpk(pa[2], pa[3]);
        u0[2] = cvtpk(pc[0], pc[1]); u0[3] = cvtpk(pc[2], pc[3]);
        u1[0] = cvtpk(pe[0], pe[1]); u1[1] = cvtpk(pe[2], pe[3]);
        u1[2] = cvtpk(pg[0], pg[1]); u1[3] = cvtpk(pg[2], pg[3]);
        short8 pf0 = __builtin_bit_cast(short8, u0);
        short8 pf1 = __builtin_bit_cast(short8, u1);

        // PV on own d-half (V stored with matching slot permutation)
#pragma unroll
        for (int dt = 0; dt < 8; ++dt) {
            acc[0][dt] = __builtin_amdgcn_mfma_f32_16x16x32_bf16(vcur[dt], pf0, acc[0][dt], 0, 0, 0);
            acc[1][dt] = __builtin_amdgcn_mfma_f32_16x16x32_bf16(vcur[dt], pf1, acc[1][dt], 0, 0, 0);
        }

        kh0 = nkh0; kl0 = nkl0; kh1 = nkh1; kl1 = nkl1;
#pragma unroll
        for (int dt = 0; dt < 8; ++dt) vcur[dt] = vnxt[dt];
    }

    // final l reduction across the 4 g-groups
    l_run0 += __shfl_xor(l_run0, 16); l_run0 += __shfl_xor(l_run0, 32);
    l_run1 += __shfl_xor(l_run1, 16); l_run1 += __shfl_xor(l_run1, 32);

    // dump raw partials, coalesced: per (qs,dt) one 1KB wave-store of a
    // 16q x 16d tile in [q][d] order at f32 offset col*16 + g*4.
    float* op = O_part + (size_t)bid * 32768 + wave * 4096;
#pragma unroll
    for (int qs = 0; qs < 2; ++qs)
#pragma unroll
        for (int dt = 0; dt < 8; ++dt) {
            int j = qs * 8 + dt;
            *(f32x4*)(op + j * 256 + col * 16 + g * 4) = acc[qs][dt];
        }
    if (dh == 0 && g == 0) {
        lsum_part[bid * 128 + qq * 32 + col]      = l_run0;
        lsum_part[bid * 128 + qq * 32 + 16 + col] = l_run1;
    }
}

// ---------------------------------------------------------------------------
// Kernel 3: epilogue. out[b,s,k,d] = gamma * (sum_ks O_part)/(sum_ks l) + x.
// ---------------------------------------------------------------------------
__global__ __launch_bounds__(256) void epi_kernel(
    const float* __restrict__ O_part, const float* __restrict__ lsum_part,
    const float* __restrict__ x, const float* __restrict__ gamma_p,
    float* __restrict__ out)
{
    int gid = blockIdx.x * 256 + threadIdx.x;   // 0..524287
    int d  = (gid & 63) * 4;
    int nl = gid >> 6;
    int b  = nl >> 12;
    int n  = nl & (N_ - 1);

    int qt = n >> 7, qq = (n >> 5) & 3, qs = (n >> 4) & 1, col = n & 15;
    int dh = d >> 7, dt = (d >> 4) & 7;
    int w = qq * 2 + dh, j = qs * 8 + dt;
    int boff = w * 4096 + j * 256 + col * 16 + (d & 15);
    int loff = qq * 32 + qs * 16 + col;

    f32x4 acc = {0.f, 0.f, 0.f, 0.f};
    float l = 0.f;
#pragma unroll
    for (int ks = 0; ks < 4; ++ks) {
        int bid = qt * 8 + b * 4 + ks;
        f32x4 p = *(const f32x4*)(O_part + (size_t)bid * 32768 + boff);
        acc[0] += p[0]; acc[1] += p[1]; acc[2] += p[2]; acc[3] += p[3];
        l += lsum_part[bid * 128 + loff];
    }
    float scale = gamma_p[0] / l;
    int s = n & 63, kk = n >> 6;
    size_t o = (((size_t)(b * S_ + s)) * K_ + kk) * D_ + d;
    f32x4 xv = *(const f32x4*)(x + o);
    f32x4 ov;
#pragma unroll
    for (int e = 0; e < 4; ++e) ov[e] = acc[e] * scale + xv[e];
    *(f32x4*)(out + o) = ov;
}

extern "C" void kernel_launch(void* const* d_in, const int* in_sizes, int n_in,
                              void* d_out, int out_size, void* d_ws, size_t ws_size,
                              hipStream_t stream) {
    const float* x  = (const float*)d_in[0];
    const float* Wq = (const float*)d_in[1];
    const float* bq = (const float*)d_in[2];
    const float* Wk = (const float*)d_in[3];
    const float* bk = (const float*)d_in[4];
    const float* Wv = (const float*)d_in[5];
    const float* bv = (const float*)d_in[6];
    const float* gm = (const float*)d_in[7];

    char* ws = (char*)d_ws;
    unsigned short* Wh   = (unsigned short*)(ws);                 // 160KB
    unsigned short* Wl   = (unsigned short*)(ws + 0x40000);       // 160KB
    float*          bcat = (float*)         (ws + 0x80000);       // 1.3KB
    unsigned short* Qh   = (unsigned short*)(ws + 0x100000);      // 512KB
    unsigned short* Ql   = (unsigned short*)(ws + 0x180000);
    unsigned short* Kh   = (unsigned short*)(ws + 0x200000);
    unsigned short* Kl   = (unsigned short*)(ws + 0x280000);
    unsigned short* Vm   = (unsigned short*)(ws + 0x300000);      // 4MB
    float*          Op   = (float*)         (ws + 0x700000);      // 32MB
    float*          lp   = (float*)         (ws + 0x2700000);     // 128KB
    float* o = (float*)d_out;

    wcvt_kernel<<<320, 256, 0, stream>>>(Wq, bq, Wk, bk, Wv, bv, Wh, Wl, bcat);
    qkv_kernel<<<512, 256, 0, stream>>>(x, Wh, Wl, bcat, Qh, Ql, Kh, Kl, Vm);
    attn_kernel<<<256, 512, 0, stream>>>(Qh, Ql, Kh, Kl, Vm, Op, lp);
    epi_kernel<<<2048, 256, 0, stream>>>(Op, lp, x, gm, o);
}

// Round 12
// 85.325 us; speedup vs baseline: 1.5891x; 1.5891x over previous
//
#include <hip/hip_runtime.h>
#include <stdint.h>
#include <math.h>

using short8   = __attribute__((ext_vector_type(8))) short;
using ushort4v = __attribute__((ext_vector_type(4))) unsigned short;
using f32x4    = __attribute__((ext_vector_type(4))) float;
using uint4v   = __attribute__((ext_vector_type(4))) unsigned int;

#define B_ 2
#define S_ 64
#define K_ 64
#define D_ 256
#define C_ 32
#define N_ 4096  /* S_*K_ */
#define LOG2E 1.4426950408889634f

__device__ __forceinline__ float b2f(unsigned short u) {
    unsigned int v = ((unsigned int)u) << 16;
    return __builtin_bit_cast(float, v);
}
__device__ __forceinline__ unsigned short f2b(float f) {   // RNE f32->bf16
    unsigned int x = __builtin_bit_cast(unsigned int, f);
    x += 0x7fffu + ((x >> 16) & 1u);
    return (unsigned short)(x >> 16);
}
// pack two f32 -> bf16x2 (a in low half, b in high), RNE, pure ALU (m240:
// scalar casts beat inline-asm v_cvt_pk — keep this schedulable)
__device__ __forceinline__ unsigned int pk2(float a, float b) {
    unsigned int xa = __builtin_bit_cast(unsigned int, a);
    unsigned int xb = __builtin_bit_cast(unsigned int, b);
    xa += 0x7fffu + ((xa >> 16) & 1u);
    xb += 0x7fffu + ((xb >> 16) & 1u);
    return (xa >> 16) | (xb & 0xffff0000u);
}

// ---------------------------------------------------------------------------
// Kernel 0: W/bias pre-convert. Concatenated out-channels: 0-31 Q (x log2e),
// 32-63 K, 64-319 V. Wh/Wl bf16 hi/lo planes [320][256]; bcat f32[320].
// ---------------------------------------------------------------------------
__global__ __launch_bounds__(256) void wcvt_kernel(
    const float* __restrict__ Wq, const float* __restrict__ bq,
    const float* __restrict__ Wk, const float* __restrict__ bk,
    const float* __restrict__ Wv, const float* __restrict__ bv,
    unsigned short* __restrict__ Wh, unsigned short* __restrict__ Wl,
    float* __restrict__ bcat)
{
    int oc = blockIdx.x;            // 0..319
    int d  = threadIdx.x;           // 0..255
    float w;
    if (oc < 32)       w = Wq[oc * 256 + d] * LOG2E;
    else if (oc < 64)  w = Wk[(oc - 32) * 256 + d];
    else               w = Wv[(oc - 64) * 256 + d];
    unsigned short h = f2b(w);
    Wh[oc * 256 + d] = h;
    Wl[oc * 256 + d] = f2b(w - b2f(h));
    if (d == 0) {
        float bb;
        if (oc < 32)      bb = bq[oc] * LOG2E;
        else if (oc < 64) bb = bk[oc - 32];
        else              bb = bv[oc - 64];
        bcat[oc] = bb;
    }
}

// ---------------------------------------------------------------------------
// Kernel 1: QKV projections. 512 blocks (one 16-token tile) x 4 waves.
// x staged once in LDS as hi/lo bf16 (XOR-swizzled); W from pre-converted
// planes. Q,K stored [B][N][C] hi/lo. V chunk-interleaved [B][N/32][D][32]
// with SLOT-PERMUTED in-chunk order: token j (in-chunk) at slot
// s = 8*((j&15)>>2) + ((j&16)>>2) + (j&3)  -- matches attn's register-P
// fragment layout so PV needs no P shuffle at all.
// ---------------------------------------------------------------------------
__global__ __launch_bounds__(256) void qkv_kernel(
    const float* __restrict__ x,
    const unsigned short* __restrict__ Wh, const unsigned short* __restrict__ Wl,
    const float* __restrict__ bcat,
    unsigned short* __restrict__ Qh, unsigned short* __restrict__ Ql,
    unsigned short* __restrict__ Kh, unsigned short* __restrict__ Kl,
    unsigned short* __restrict__ Vm)
{
    __shared__ unsigned short lxh[16 * 256];   // [tok][d] bf16-hi, swizzled
    __shared__ unsigned short lxl[16 * 256];   // bf16-lo

    int tid = threadIdx.x;
    int bid = blockIdx.x;
    int b  = bid >> 8;
    int n0 = (bid & 255) << 4;

    // ---- stage x tile: thread -> (token tt, 16-d group dg0) ----
    {
        int tt = tid >> 4, dg0 = (tid & 15) * 16;
        int n = n0 + tt;
        int s = n & 63, kk = n >> 6;
        const float* xr = x + (((size_t)(b * S_ + s)) * K_ + kk) * D_ + dg0;
        short8 h0, l0, h1, l1;
#pragma unroll
        for (int e = 0; e < 8; ++e) {
            float v = xr[e];
            unsigned short hh = f2b(v);
            h0[e] = (short)hh; l0[e] = (short)f2b(v - b2f(hh));
        }
#pragma unroll
        for (int e = 0; e < 8; ++e) {
            float v = xr[8 + e];
            unsigned short hh = f2b(v);
            h1[e] = (short)hh; l1[e] = (short)f2b(v - b2f(hh));
        }
        int m0 = dg0 >> 3;                       // 16B-granule index (even)
        int sw0 = ((m0 ^ (tt & 7)) << 3);
        int sw1 = (((m0 + 1) ^ (tt & 7)) << 3);
        *(short8*)(lxh + tt * 256 + sw0) = h0;
        *(short8*)(lxh + tt * 256 + sw1) = h1;
        *(short8*)(lxl + tt * 256 + sw0) = l0;
        *(short8*)(lxl + tt * 256 + sw1) = l1;
    }
    __syncthreads();

    int wave = tid >> 6, lane = tid & 63;
    int col = lane & 15, g = lane >> 4;

#pragma unroll
    for (int i = 0; i < 5; ++i) {
        int ct = wave + i * 4;                   // 0..19
        int oc0 = ct * 16;
        const unsigned short* whr = Wh + (size_t)(oc0 + col) * 256;
        const unsigned short* wlr = Wl + (size_t)(oc0 + col) * 256;
        f32x4 acc = {0.f, 0.f, 0.f, 0.f};

        if (ct < 4) {                            // Q/K: split-bf16 3-chain
#pragma unroll
            for (int dc = 0; dc < 8; ++dc) {
                int sw = (((dc * 4 + g) ^ (col & 7)) << 3);
                short8 xh8 = *(const short8*)(lxh + col * 256 + sw);
                short8 xl8 = *(const short8*)(lxl + col * 256 + sw);
                short8 wh8 = *(const short8*)(whr + dc * 32 + g * 8);
                short8 wl8 = *(const short8*)(wlr + dc * 32 + g * 8);
                acc = __builtin_amdgcn_mfma_f32_16x16x32_bf16(xl8, wh8, acc, 0, 0, 0);
                acc = __builtin_amdgcn_mfma_f32_16x16x32_bf16(xh8, wl8, acc, 0, 0, 0);
                acc = __builtin_amdgcn_mfma_f32_16x16x32_bf16(xh8, wh8, acc, 0, 0, 0);
            }
            float bb = bcat[oc0 + col];
            unsigned short* Th = (ct < 2) ? Qh : Kh;
            unsigned short* Tl = (ct < 2) ? Ql : Kl;
            int c0 = (ct & 1) * 16;
#pragma unroll
            for (int r = 0; r < 4; ++r) {
                int tok = n0 + g * 4 + r;
                float v = acc[r] + bb;
                unsigned short hh = f2b(v);
                size_t idx = ((size_t)b * N_ + tok) * C_ + c0 + col;
                Th[idx] = hh;
                Tl[idx] = f2b(v - b2f(hh));
            }
        } else {                                 // V: single bf16
#pragma unroll
            for (int dc = 0; dc < 8; ++dc) {
                int sw = (((dc * 4 + g) ^ (col & 7)) << 3);
                short8 xh8 = *(const short8*)(lxh + col * 256 + sw);
                short8 wh8 = *(const short8*)(whr + dc * 32 + g * 8);
                acc = __builtin_amdgcn_mfma_f32_16x16x32_bf16(xh8, wh8, acc, 0, 0, 0);
            }
            float bb = bcat[oc0 + col];
            int c0 = oc0 - 64;
            ushort4v st;
#pragma unroll
            for (int r = 0; r < 4; ++r) st[r] = f2b(acc[r] + bb);
            int tok0 = n0 + g * 4;
            int s0 = 8 * g + ((n0 & 16) >> 2);   // slot-permuted in-chunk pos
            size_t vaddr = (((size_t)b * (N_ / 32) + (tok0 >> 5)) * D_ + c0 + col) * 32
                         + s0;
            *(ushort4v*)(Vm + vaddr) = st;
        }
    }
}

// ---------------------------------------------------------------------------
// Kernel 2: flash attention, 128-q tiles x key-split-4, barrier-free,
// REGISTER-ONLY P (slot-permuted V). sched_barrier(0) pins the K/V prefetch
// issue ABOVE the compute (R11 lesson: without it the compiler sinks the
// loads to their use, killing the pipeline -- VGPR 112->76 signature).
// P packed with pure-ALU pk2 (m240: scalar beats inline-asm cvt_pk).
// 256 blocks: bid&7=(b*4+ks) per XCD; 8 waves = 4 q-quarters x 2 d-halves.
// exp2-domain softmax (Q pre-scaled), no-max; l reduced once after the loop.
// ---------------------------------------------------------------------------
__global__ __launch_bounds__(512, 2) void attn_kernel(
    const unsigned short* __restrict__ Qh, const unsigned short* __restrict__ Ql,
    const unsigned short* __restrict__ Kh, const unsigned short* __restrict__ Kl,
    const unsigned short* __restrict__ Vm,
    float* __restrict__ O_part, float* __restrict__ lsum_part)
{
    int tid  = threadIdx.x;
    int wave = tid >> 6;
    int lane = tid & 63;
    int col = lane & 15, g = lane >> 4;
    int qq = wave >> 1;           // q-quarter 0..3
    int dh = wave & 1;            // d-half 0..1
    int dbase = dh * 128;

    int bid = blockIdx.x;
    int x7 = bid & 7;
    int b  = x7 >> 2;
    int ks = x7 & 3;
    int qt = bid >> 3;            // 0..31 (q-tile within batch)
    int q0 = qt * 128 + qq * 32;
    int jbase = ks * (N_ / 4);

    size_t qoff0 = ((size_t)b * N_ + q0 + col) * C_ + g * 8;
    size_t qoff1 = ((size_t)b * N_ + q0 + 16 + col) * C_ + g * 8;
    short8 qfh0 = *(const short8*)(Qh + qoff0);
    short8 qfl0 = *(const short8*)(Ql + qoff0);
    short8 qfh1 = *(const short8*)(Qh + qoff1);
    short8 qfl1 = *(const short8*)(Ql + qoff1);

    f32x4 acc[2][8];
#pragma unroll
    for (int qs = 0; qs < 2; ++qs)
#pragma unroll
        for (int dt = 0; dt < 8; ++dt) acc[qs][dt] = (f32x4){0.f, 0.f, 0.f, 0.f};
    float l_run0 = 0.f, l_run1 = 0.f;   // per-lane partials (reduced at end)

    const unsigned short* kbh = Kh + (size_t)b * N_ * C_;
    const unsigned short* kbl = Kl + (size_t)b * N_ * C_;
    const unsigned short* vb  = Vm + (size_t)b * N_ * D_;   // [N/32][D][32]

    auto kaddr0 = [&](int it) { return (size_t)(jbase + it * 32 + col) * C_ + g * 8; };
    auto kaddr1 = [&](int it) { return (size_t)(jbase + it * 32 + 16 + col) * C_ + g * 8; };
    auto vaddr  = [&](int it) {
        return (size_t)(ks * 32 + it) * (D_ * 32) + (size_t)(dbase + col) * 32 + g * 8;
    };

    // prologue: K(0), V(0)
    short8 kh0 = *(const short8*)(kbh + kaddr0(0));
    short8 kl0 = *(const short8*)(kbl + kaddr0(0));
    short8 kh1 = *(const short8*)(kbh + kaddr1(0));
    short8 kl1 = *(const short8*)(kbl + kaddr1(0));
    short8 vcur[8];
    {
        const unsigned short* vp = vb + vaddr(0);
#pragma unroll
        for (int dt = 0; dt < 8; ++dt)
            vcur[dt] = *(const short8*)(vp + dt * (16 * 32));
    }

    for (int it = 0; it < 32; ++it) {
        // issue next iteration's K and V loads, then PIN them above compute
        short8 nkh0, nkl0, nkh1, nkl1, vnxt[8];
        int itn = (it + 1 < 32) ? it + 1 : 0;
        nkh0 = *(const short8*)(kbh + kaddr0(itn));
        nkl0 = *(const short8*)(kbl + kaddr0(itn));
        nkh1 = *(const short8*)(kbh + kaddr1(itn));
        nkl1 = *(const short8*)(kbl + kaddr1(itn));
        {
            const unsigned short* vp = vb + vaddr(itn);
#pragma unroll
            for (int dt = 0; dt < 8; ++dt)
                vnxt[dt] = *(const short8*)(vp + dt * (16 * 32));
        }
        __builtin_amdgcn_sched_barrier(0);   // loads stay issued up here

        // QK^T (split-bf16 3-chain): D[key][q], exp2-domain scores
        f32x4 z = {0.f, 0.f, 0.f, 0.f};
        f32x4 s00 = __builtin_amdgcn_mfma_f32_16x16x32_bf16(kl0, qfh0, z, 0, 0, 0);
        s00 = __builtin_amdgcn_mfma_f32_16x16x32_bf16(kh0, qfl0, s00, 0, 0, 0);
        s00 = __builtin_amdgcn_mfma_f32_16x16x32_bf16(kh0, qfh0, s00, 0, 0, 0);
        f32x4 s01 = __builtin_amdgcn_mfma_f32_16x16x32_bf16(kl1, qfh0, z, 0, 0, 0);
        s01 = __builtin_amdgcn_mfma_f32_16x16x32_bf16(kh1, qfl0, s01, 0, 0, 0);
        s01 = __builtin_amdgcn_mfma_f32_16x16x32_bf16(kh1, qfh0, s01, 0, 0, 0);
        f32x4 s10 = __builtin_amdgcn_mfma_f32_16x16x32_bf16(kl0, qfh1, z, 0, 0, 0);
        s10 = __builtin_amdgcn_mfma_f32_16x16x32_bf16(kh0, qfl1, s10, 0, 0, 0);
        s10 = __builtin_amdgcn_mfma_f32_16x16x32_bf16(kh0, qfh1, s10, 0, 0, 0);
        f32x4 s11 = __builtin_amdgcn_mfma_f32_16x16x32_bf16(kl1, qfh1, z, 0, 0, 0);
        s11 = __builtin_amdgcn_mfma_f32_16x16x32_bf16(kh1, qfl1, s11, 0, 0, 0);
        s11 = __builtin_amdgcn_mfma_f32_16x16x32_bf16(kh1, qfh1, s11, 0, 0, 0);

        // p = exp2(s'); |s'| <~50, clamp 80 is pure safety
        float pa[4], pc[4], pe[4], pg[4];
#pragma unroll
        for (int r = 0; r < 4; ++r) {
            pa[r] = exp2f(fminf(s00[r], 80.f));
            pc[r] = exp2f(fminf(s01[r], 80.f));
            pe[r] = exp2f(fminf(s10[r], 80.f));
            pg[r] = exp2f(fminf(s11[r], 80.f));
        }
        l_run0 += (pa[0] + pa[1]) + (pa[2] + pa[3]) + (pc[0] + pc[1]) + (pc[2] + pc[3]);
        l_run1 += (pe[0] + pe[1]) + (pe[2] + pe[3]) + (pg[0] + pg[1]) + (pg[2] + pg[3]);

        // pack P straight into PV B-fragments (slot-permuted; zero shuffle)
        uint4v u0, u1;
        u0[0] = pk2(pa[0], pa[1]); u0[1] = pk2(pa[2], pa[3]);
        u0[2] = pk2(pc[0], pc[1]); u0[3] = pk2(pc[2], pc[3]);
        u1[0] = pk2(pe[0], pe[1]); u1[1] = pk2(pe[2], pe[3]);
        u1[2] = pk2(pg[0], pg[1]); u1[3] = pk2(pg[2], pg[3]);
        short8 pf0 = __builtin_bit_cast(short8, u0);
        short8 pf1 = __builtin_bit_cast(short8, u1);

        // PV on own d-half (V stored with matching slot permutation)
#pragma unroll
        for (int dt = 0; dt < 8; ++dt) {
            acc[0][dt] = __builtin_amdgcn_mfma_f32_16x16x32_bf16(vcur[dt], pf0, acc[0][dt], 0, 0, 0);
            acc[1][dt] = __builtin_amdgcn_mfma_f32_16x16x32_bf16(vcur[dt], pf1, acc[1][dt], 0, 0, 0);
        }

        kh0 = nkh0; kl0 = nkl0; kh1 = nkh1; kl1 = nkl1;
#pragma unroll
        for (int dt = 0; dt < 8; ++dt) vcur[dt] = vnxt[dt];
    }

    // final l reduction across the 4 g-groups
    l_run0 += __shfl_xor(l_run0, 16); l_run0 += __shfl_xor(l_run0, 32);
    l_run1 += __shfl_xor(l_run1, 16); l_run1 += __shfl_xor(l_run1, 32);

    // dump raw partials, coalesced: per (qs,dt) one 1KB wave-store of a
    // 16q x 16d tile in [q][d] order at f32 offset col*16 + g*4.
    float* op = O_part + (size_t)bid * 32768 + wave * 4096;
#pragma unroll
    for (int qs = 0; qs < 2; ++qs)
#pragma unroll
        for (int dt = 0; dt < 8; ++dt) {
            int j = qs * 8 + dt;
            *(f32x4*)(op + j * 256 + col * 16 + g * 4) = acc[qs][dt];
        }
    if (dh == 0 && g == 0) {
        lsum_part[bid * 128 + qq * 32 + col]      = l_run0;
        lsum_part[bid * 128 + qq * 32 + 16 + col] = l_run1;
    }
}

// ---------------------------------------------------------------------------
// Kernel 3: epilogue. out[b,s,k,d] = gamma * (sum_ks O_part)/(sum_ks l) + x.
// ---------------------------------------------------------------------------
__global__ __launch_bounds__(256) void epi_kernel(
    const float* __restrict__ O_part, const float* __restrict__ lsum_part,
    const float* __restrict__ x, const float* __restrict__ gamma_p,
    float* __restrict__ out)
{
    int gid = blockIdx.x * 256 + threadIdx.x;   // 0..524287
    int d  = (gid & 63) * 4;
    int nl = gid >> 6;
    int b  = nl >> 12;
    int n  = nl & (N_ - 1);

    int qt = n >> 7, qq = (n >> 5) & 3, qs = (n >> 4) & 1, col = n & 15;
    int dh = d >> 7, dt = (d >> 4) & 7;
    int w = qq * 2 + dh, j = qs * 8 + dt;
    int boff = w * 4096 + j * 256 + col * 16 + (d & 15);
    int loff = qq * 32 + qs * 16 + col;

    f32x4 acc = {0.f, 0.f, 0.f, 0.f};
    float l = 0.f;
#pragma unroll
    for (int ks = 0; ks < 4; ++ks) {
        int bid = qt * 8 + b * 4 + ks;
        f32x4 p = *(const f32x4*)(O_part + (size_t)bid * 32768 + boff);
        acc[0] += p[0]; acc[1] += p[1]; acc[2] += p[2]; acc[3] += p[3];
        l += lsum_part[bid * 128 + loff];
    }
    float scale = gamma_p[0] / l;
    int s = n & 63, kk = n >> 6;
    size_t o = (((size_t)(b * S_ + s)) * K_ + kk) * D_ + d;
    f32x4 xv = *(const f32x4*)(x + o);
    f32x4 ov;
#pragma unroll
    for (int e = 0; e < 4; ++e) ov[e] = acc[e] * scale + xv[e];
    *(f32x4*)(out + o) = ov;
}

extern "C" void kernel_launch(void* const* d_in, const int* in_sizes, int n_in,
                              void* d_out, int out_size, void* d_ws, size_t ws_size,
                              hipStream_t stream) {
    const float* x  = (const float*)d_in[0];
    const float* Wq = (const float*)d_in[1];
    const float* bq = (const float*)d_in[2];
    const float* Wk = (const float*)d_in[3];
    const float* bk = (const float*)d_in[4];
    const float* Wv = (const float*)d_in[5];
    const float* bv = (const float*)d_in[6];
    const float* gm = (const float*)d_in[7];

    char* ws = (char*)d_ws;
    unsigned short* Wh   = (unsigned short*)(ws);                 // 160KB
    unsigned short* Wl   = (unsigned short*)(ws + 0x40000);       // 160KB
    float*          bcat = (float*)         (ws + 0x80000);       // 1.3KB
    unsigned short* Qh   = (unsigned short*)(ws + 0x100000);      // 512KB
    unsigned short* Ql   = (unsigned short*)(ws + 0x180000);
    unsigned short* Kh   = (unsigned short*)(ws + 0x200000);
    unsigned short* Kl   = (unsigned short*)(ws + 0x280000);
    unsigned short* Vm   = (unsigned short*)(ws + 0x300000);      // 4MB
    float*          Op   = (float*)         (ws + 0x700000);      // 32MB
    float*          lp   = (float*)         (ws + 0x2700000);     // 128KB
    float* o = (float*)d_out;

    wcvt_kernel<<<320, 256, 0, stream>>>(Wq, bq, Wk, bk, Wv, bv, Wh, Wl, bcat);
    qkv_kernel<<<512, 256, 0, stream>>>(x, Wh, Wl, bcat, Qh, Ql, Kh, Kl, Vm);
    attn_kernel<<<256, 512, 0, stream>>>(Qh, Ql, Kh, Kl, Vm, Op, lp);
    epi_kernel<<<2048, 256, 0, stream>>>(Op, lp, x, gm, o);
}